// Round 1
// baseline (5071.224 us; speedup 1.0000x reference)
//
#include <hip/hip_runtime.h>

#define NV 500000
#define KOFF 27
#define CIN_ 32
#define COUT_ 64
#define EPS_ 1e-5f

typedef __attribute__((ext_vector_type(8))) _Float16 half8;
typedef __attribute__((ext_vector_type(4))) float floatx4;

// ws layout: y1h NV*64 f16 | xh NV*32 f16 | wT1 27*64*32 f16 | wT2 27*64*64 f16 | st 768 f32

__global__ void zero_stats_kernel(float* __restrict__ s) {
  if (threadIdx.x < 384) s[threadIdx.x] = 0.f;
}

__global__ __launch_bounds__(256) void cast_x_kernel(
    const float* __restrict__ x, _Float16* __restrict__ xh) {
  size_t q = (size_t)blockIdx.x * 256 + threadIdx.x;
  if (q >= (size_t)NV * CIN_ / 8) return;
  const float4* xp = (const float4*)x;
  float4 a = xp[2 * q], b = xp[2 * q + 1];
  half8 h;
  h[0] = (_Float16)a.x; h[1] = (_Float16)a.y; h[2] = (_Float16)a.z; h[3] = (_Float16)a.w;
  h[4] = (_Float16)b.x; h[5] = (_Float16)b.y; h[6] = (_Float16)b.z; h[7] = (_Float16)b.w;
  ((half8*)xh)[q] = h;
}

// wT[k][co][ci] = (f16) w[k][ci][co]
__global__ void wtrans_kernel(const float* __restrict__ w,
                              _Float16* __restrict__ wT, int CI) {
  int t = blockIdx.x * 256 + threadIdx.x;
  int total = KOFF * CI * COUT_;
  if (t >= total) return;
  int k = t / (CI * COUT_);
  int r = t % (CI * COUT_);
  int co = r / CI;
  int ci = r % CI;
  wT[t] = (_Float16)w[(k * CI + ci) * COUT_ + co];
}

// ---- conv v4: 512-thr blocks, 16 voxels/wave (1 group), fused BN stats ----
// Register budget per wave: acc 16 + ring (<=24) + j (<=7) + addr ~15 -> 3-4
// blocks/CU (24-32 waves) vs v3's 1 block/CU (16 waves).

template<int CI>
__device__ __forceinline__ void stageB_v4(const _Float16* __restrict__ wT,
                                          _Float16* __restrict__ lds,
                                          int k0, int kp, int tid) {
  __syncthreads();  // all waves done reading previous phase's LDS
  const int segs = CI / 8;
  const int chunks = kp * COUT_ * segs;
  for (int idx = tid; idx < chunks; idx += 512) {
    int row = idx / segs;
    int s = idx - row * segs;
    half8 v = *(const half8*)(wT + ((size_t)k0 * COUT_ + row) * CI + s * 8);
    *(half8*)(lds + (size_t)row * (CI + 8) + s * 8) = v;
  }
  __syncthreads();
}

template<int CI, int KPC, int D>
__device__ __forceinline__ void run_phase_v4(
    const half8* __restrict__ fp, const int* __restrict__ nbr,
    const _Float16* __restrict__ lds, int k0,
    int v0, int m, int quad, floatx4 acc[4]) {
  constexpr int SEG = CI / 32;
  constexpr int ROWH8 = CI / 8;

  // preload all phase indices first (vmcnt drains in order)
  int j0[KPC];
#pragma unroll
  for (int k = 0; k < KPC; ++k) j0[k] = nbr[(k0 + k) * NV + v0] * ROWH8;

  half8 ring[D][SEG];
#pragma unroll
  for (int p = 0; p < D; ++p)
#pragma unroll
    for (int s = 0; s < SEG; ++s)
      ring[p][s] = fp[(size_t)j0[p] + s * 4 + quad];

#pragma unroll
  for (int k = 0; k < KPC; ++k) {
    const _Float16* bk = lds + (size_t)k * COUT_ * (CI + 8);
#pragma unroll
    for (int s = 0; s < SEG; ++s)
#pragma unroll
      for (int nf = 0; nf < 4; ++nf) {
        half8 bf = *(const half8*)(bk + (nf * 16 + m) * (CI + 8) + s * 32 + quad * 8);
        acc[nf] = __builtin_amdgcn_mfma_f32_16x16x32_f16(ring[k % D][s], bf, acc[nf], 0, 0, 0);
      }
    if (k + D < KPC) {
#pragma unroll
      for (int s = 0; s < SEG; ++s)
        ring[k % D][s] = fp[(size_t)j0[k + D] + s * 4 + quad];
    }
  }
}

template<int CI, bool WF16>
__global__ __launch_bounds__(512, (CI == 32) ? 8 : 7) void conv_mfma_v4(
    const _Float16* __restrict__ feats, const int* __restrict__ nbr,
    const _Float16* __restrict__ wT, float* __restrict__ outF,
    _Float16* __restrict__ outH, float* __restrict__ stOut) {
  // CI=64: 7 phases of <=4 k -> 4*64*72 halfs = 36.9 KB
  // CI=32: 4 phases of <=7 k -> 7*64*40 halfs = 35.8 KB
  constexpr int LDSH = (CI == 64) ? 4 * 64 * 72 : 7 * 64 * 40;
  __shared__ __align__(16) _Float16 ldsB[LDSH];
  __shared__ float bs[128];  // block-level stats reduce (sum | sumsq)

  int tid = threadIdx.x;
  int wave = tid >> 6, lane = tid & 63;
  int m = lane & 15, quad = lane >> 4;
  int vbase = (blockIdx.x * 8 + wave) * 16;  // 16 voxels per wave
  int v0 = vbase + m;
  v0 = v0 < NV ? v0 : NV - 1;
  const half8* fp = (const half8*)feats;

  if (tid < 128) bs[tid] = 0.f;  // ordered by stageB's first __syncthreads

  floatx4 acc[4];
#pragma unroll
  for (int nf = 0; nf < 4; ++nf) acc[nf] = (floatx4){0.f, 0.f, 0.f, 0.f};

  if constexpr (CI == 64) {
    stageB_v4<CI>(wT, ldsB, 0, 4, tid);  run_phase_v4<CI, 4, 3>(fp, nbr, ldsB, 0,  v0, m, quad, acc);
    stageB_v4<CI>(wT, ldsB, 4, 4, tid);  run_phase_v4<CI, 4, 3>(fp, nbr, ldsB, 4,  v0, m, quad, acc);
    stageB_v4<CI>(wT, ldsB, 8, 4, tid);  run_phase_v4<CI, 4, 3>(fp, nbr, ldsB, 8,  v0, m, quad, acc);
    stageB_v4<CI>(wT, ldsB, 12, 4, tid); run_phase_v4<CI, 4, 3>(fp, nbr, ldsB, 12, v0, m, quad, acc);
    stageB_v4<CI>(wT, ldsB, 16, 4, tid); run_phase_v4<CI, 4, 3>(fp, nbr, ldsB, 16, v0, m, quad, acc);
    stageB_v4<CI>(wT, ldsB, 20, 4, tid); run_phase_v4<CI, 4, 3>(fp, nbr, ldsB, 20, v0, m, quad, acc);
    stageB_v4<CI>(wT, ldsB, 24, 3, tid); run_phase_v4<CI, 3, 3>(fp, nbr, ldsB, 24, v0, m, quad, acc);
  } else {
    stageB_v4<CI>(wT, ldsB, 0, 7, tid);  run_phase_v4<CI, 7, 4>(fp, nbr, ldsB, 0,  v0, m, quad, acc);
    stageB_v4<CI>(wT, ldsB, 7, 7, tid);  run_phase_v4<CI, 7, 4>(fp, nbr, ldsB, 7,  v0, m, quad, acc);
    stageB_v4<CI>(wT, ldsB, 14, 7, tid); run_phase_v4<CI, 7, 4>(fp, nbr, ldsB, 14, v0, m, quad, acc);
    stageB_v4<CI>(wT, ldsB, 21, 6, tid); run_phase_v4<CI, 6, 4>(fp, nbr, ldsB, 21, v0, m, quad, acc);
  }

  // epilogue: store + fused BN stats (sum / sumsq per channel)
  float s4[4], q4[4];
#pragma unroll
  for (int nf = 0; nf < 4; ++nf) {
    float s = 0.f, q = 0.f;
#pragma unroll
    for (int r = 0; r < 4; ++r) {
      int row = vbase + quad * 4 + r;
      if (row < NV) {
        float v = acc[nf][r];
        size_t o = (size_t)row * COUT_ + nf * 16 + m;
        if constexpr (WF16) outH[o] = (_Float16)v;
        else outF[o] = v;
        s += v;
        q = fmaf(v, v, q);
      }
    }
    s4[nf] = s; q4[nf] = q;
  }
  // reduce over the 4 quads: lanes m, m+16, m+32, m+48 hold channel nf*16+m
#pragma unroll
  for (int nf = 0; nf < 4; ++nf) {
    s4[nf] += __shfl_xor(s4[nf], 16); s4[nf] += __shfl_xor(s4[nf], 32);
    q4[nf] += __shfl_xor(q4[nf], 16); q4[nf] += __shfl_xor(q4[nf], 32);
  }
  if (quad == 0) {
#pragma unroll
    for (int nf = 0; nf < 4; ++nf) {
      atomicAdd(&bs[nf * 16 + m], s4[nf]);
      atomicAdd(&bs[64 + nf * 16 + m], q4[nf]);
    }
  }
  __syncthreads();
  if (tid < 128) atomicAdd(&stOut[tid], bs[tid]);
}

// ---- ident stats / BN finalize / epilogue kernels ----

__global__ __launch_bounds__(256) void ident_stats_kernel(
    const float* __restrict__ x, const float* __restrict__ wid,
    float* __restrict__ sums) {
  int lane = threadIdx.x & 63;
  int wv = blockIdx.x * 4 + (threadIdx.x >> 6);
  int nw = gridDim.x * 4;
  float wcol[CIN_];
#pragma unroll
  for (int ci = 0; ci < CIN_; ++ci) wcol[ci] = wid[ci * COUT_ + lane];
  float s = 0.f, ss = 0.f;
  for (int v = wv; v < NV; v += nw) {
    const float* xr = x + (size_t)v * CIN_;
    float d = 0.f;
#pragma unroll
    for (int ci = 0; ci < CIN_; ++ci) d = fmaf(xr[ci], wcol[ci], d);
    s += d;
    ss = fmaf(d, d, ss);
  }
  __shared__ float ls[128];
  if (threadIdx.x < 128) ls[threadIdx.x] = 0.f;
  __syncthreads();
  atomicAdd(&ls[lane], s);
  atomicAdd(&ls[64 + lane], ss);
  __syncthreads();
  if (threadIdx.x < 128) atomicAdd(&sums[threadIdx.x], ls[threadIdx.x]);
}

__global__ void finalize_kernel(const float* __restrict__ sums,
                                const float* __restrict__ g,
                                const float* __restrict__ b,
                                float* __restrict__ out) {
  int c = threadIdx.x;
  float m = sums[c] * (1.0f / NV);
  float var = sums[64 + c] * (1.0f / NV) - m * m;
  float sc = g[c] / sqrtf(var + EPS_);
  out[c] = sc;
  out[64 + c] = b[c] - m * sc;
}

__global__ __launch_bounds__(256) void bnrelu_f16_kernel(
    _Float16* __restrict__ y, const float* __restrict__ scsh) {
  size_t q = (size_t)blockIdx.x * 256 + threadIdx.x;
  if (q >= (size_t)NV * COUT_ / 8) return;
  int c0 = (int)(q & 7) * 8;
  half8 v = ((const half8*)y)[q];
#pragma unroll
  for (int jj = 0; jj < 8; ++jj) {
    float f = fmaxf(fmaf((float)v[jj], scsh[c0 + jj], scsh[64 + c0 + jj]), 0.f);
    v[jj] = (_Float16)f;
  }
  ((half8*)y)[q] = v;
}

__global__ __launch_bounds__(256) void final_kernel(
    const float* __restrict__ x, const float* __restrict__ wid,
    float* __restrict__ y2out, const float* __restrict__ ss2,
    const float* __restrict__ ssid) {
  int lane = threadIdx.x & 63;
  int wv = blockIdx.x * 4 + (threadIdx.x >> 6);
  int nw = gridDim.x * 4;
  float wcol[CIN_];
#pragma unroll
  for (int ci = 0; ci < CIN_; ++ci) wcol[ci] = wid[ci * COUT_ + lane];
  float sc2 = ss2[lane], sh2 = ss2[64 + lane];
  float sci = ssid[lane], shi = ssid[64 + lane];
  for (int v = wv; v < NV; v += nw) {
    const float* xr = x + (size_t)v * CIN_;
    float d = 0.f;
#pragma unroll
    for (int ci = 0; ci < CIN_; ++ci) d = fmaf(xr[ci], wcol[ci], d);
    size_t o = (size_t)v * COUT_ + lane;
    float r = fmaf(y2out[o], sc2, sh2) + fmaf(d, sci, shi);
    y2out[o] = fmaxf(r, 0.f);
  }
}

extern "C" void kernel_launch(void* const* d_in, const int* in_sizes, int n_in,
                              void* d_out, int out_size, void* d_ws, size_t ws_size,
                              hipStream_t stream) {
  const float* x   = (const float*)d_in[0];
  const int*   nbr = (const int*)d_in[1];
  const float* w1  = (const float*)d_in[2];
  const float* g1  = (const float*)d_in[3];
  const float* b1  = (const float*)d_in[4];
  const float* w2  = (const float*)d_in[5];
  const float* g2  = (const float*)d_in[6];
  const float* b2  = (const float*)d_in[7];
  const float* wid = (const float*)d_in[8];
  const float* gid = (const float*)d_in[9];
  const float* bid = (const float*)d_in[10];
  float* out = (float*)d_out;

  _Float16* y1h = (_Float16*)d_ws;
  _Float16* xh  = y1h + (size_t)NV * COUT_;
  _Float16* wT1 = xh + (size_t)NV * CIN_;
  _Float16* wT2 = wT1 + KOFF * COUT_ * CIN_;
  float*    st  = (float*)(wT2 + KOFF * COUT_ * COUT_);

  const int NWG = (NV + 127) / 128;  // 512 thr = 8 waves x 16 voxels

  zero_stats_kernel<<<1, 384, 0, stream>>>(st);
  cast_x_kernel<<<(NV * CIN_ / 8 + 255) / 256, 256, 0, stream>>>(x, xh);
  wtrans_kernel<<<(KOFF * CIN_ * COUT_ + 255) / 256, 256, 0, stream>>>(w1, wT1, CIN_);
  wtrans_kernel<<<(KOFF * COUT_ * COUT_ + 255) / 256, 256, 0, stream>>>(w2, wT2, COUT_);

  // conv1 with fused BN1 stats -> st[0:128)
  conv_mfma_v4<CIN_, true><<<NWG, 512, 0, stream>>>(xh, nbr, wT1, nullptr, y1h, st + 0);
  ident_stats_kernel<<<2048, 256, 0, stream>>>(x, wid, st + 256);
  finalize_kernel<<<1, 64, 0, stream>>>(st + 0, g1, b1, st + 384);
  finalize_kernel<<<1, 64, 0, stream>>>(st + 256, gid, bid, st + 640);
  bnrelu_f16_kernel<<<(NV * COUT_ / 8 + 255) / 256, 256, 0, stream>>>(y1h, st + 384);

  // conv2 with fused BN2 stats -> st[128:256)
  conv_mfma_v4<COUT_, false><<<NWG, 512, 0, stream>>>(y1h, nbr, wT2, out, nullptr, st + 128);
  finalize_kernel<<<1, 64, 0, stream>>>(st + 128, g2, b2, st + 512);
  final_kernel<<<4096, 256, 0, stream>>>(x, wid, out, st + 512, st + 640);
}

// Round 2
// 4732.449 us; speedup vs baseline: 1.0716x; 1.0716x over previous
//
#include <hip/hip_runtime.h>

#define NV 500000
#define KOFF 27
#define CIN_ 32
#define COUT_ 64
#define EPS_ 1e-5f

typedef __attribute__((ext_vector_type(8))) _Float16 half8;
typedef __attribute__((ext_vector_type(4))) float floatx4;

// ws layout: y1h NV*64 f16 | xh NV*32 f16 | wT1 27*64*32 f16 | wT2 27*64*64 f16 | st 768 f32

__global__ void zero_stats_kernel(float* __restrict__ s) {
  if (threadIdx.x < 384) s[threadIdx.x] = 0.f;
}

__global__ __launch_bounds__(256) void cast_x_kernel(
    const float* __restrict__ x, _Float16* __restrict__ xh) {
  size_t q = (size_t)blockIdx.x * 256 + threadIdx.x;
  if (q >= (size_t)NV * CIN_ / 8) return;
  const float4* xp = (const float4*)x;
  float4 a = xp[2 * q], b = xp[2 * q + 1];
  half8 h;
  h[0] = (_Float16)a.x; h[1] = (_Float16)a.y; h[2] = (_Float16)a.z; h[3] = (_Float16)a.w;
  h[4] = (_Float16)b.x; h[5] = (_Float16)b.y; h[6] = (_Float16)b.z; h[7] = (_Float16)b.w;
  ((half8*)xh)[q] = h;
}

// wT[k][co][ci] = (f16) w[k][ci][co]
__global__ void wtrans_kernel(const float* __restrict__ w,
                              _Float16* __restrict__ wT, int CI) {
  int t = blockIdx.x * 256 + threadIdx.x;
  int total = KOFF * CI * COUT_;
  if (t >= total) return;
  int k = t / (CI * COUT_);
  int r = t % (CI * COUT_);
  int co = r / CI;
  int ci = r % CI;
  wT[t] = (_Float16)w[(k * CI + ci) * COUT_ + co];
}

// ---- conv v5: 512-thr blocks, 16 voxels/wave, fused BN stats, SPILL-FREE ----
// Round-1 lesson: __launch_bounds__(512,7/8) capped VGPRs at ~64-73 and the
// allocator spilled the ring to scratch (WRITE_SIZE 125MB -> 6GB). v5 uses
// min-waves=6 (cap ~80-85, 3 blocks/CU = 24 waves) and a depth-2 ring
// (k&1 indexing, compile-time) to stay comfortably under the cap.

template<int CI>
__device__ __forceinline__ void stageB_v5(const _Float16* __restrict__ wT,
                                          _Float16* __restrict__ lds,
                                          int k0, int kp, int tid) {
  __syncthreads();  // all waves done reading previous phase's LDS
  const int segs = CI / 8;
  const int chunks = kp * COUT_ * segs;
  for (int idx = tid; idx < chunks; idx += 512) {
    int row = idx / segs;
    int s = idx - row * segs;
    half8 v = *(const half8*)(wT + ((size_t)k0 * COUT_ + row) * CI + s * 8);
    *(half8*)(lds + (size_t)row * (CI + 8) + s * 8) = v;
  }
  __syncthreads();
}

template<int CI, int KPC>
__device__ __forceinline__ void run_phase_v5(
    const half8* __restrict__ fp, const int* __restrict__ nbr,
    const _Float16* __restrict__ lds, int k0,
    int v0, int m, int quad, floatx4 acc[4]) {
  constexpr int SEG = CI / 32;
  constexpr int ROWH8 = CI / 8;

  // preload all phase indices first (vmcnt drains in order)
  int j0[KPC];
#pragma unroll
  for (int k = 0; k < KPC; ++k) j0[k] = nbr[(k0 + k) * NV + v0] * ROWH8;

  // depth-2 ring, index k&1 (always compile-time after unroll)
  half8 ring[2][SEG];
#pragma unroll
  for (int p = 0; p < 2; ++p)
#pragma unroll
    for (int s = 0; s < SEG; ++s)
      ring[p][s] = fp[(size_t)j0[p] + s * 4 + quad];

#pragma unroll
  for (int k = 0; k < KPC; ++k) {
    const _Float16* bk = lds + (size_t)k * COUT_ * (CI + 8);
#pragma unroll
    for (int s = 0; s < SEG; ++s)
#pragma unroll
      for (int nf = 0; nf < 4; ++nf) {
        half8 bf = *(const half8*)(bk + (nf * 16 + m) * (CI + 8) + s * 32 + quad * 8);
        acc[nf] = __builtin_amdgcn_mfma_f32_16x16x32_f16(ring[k & 1][s], bf, acc[nf], 0, 0, 0);
      }
    if (k + 2 < KPC) {
#pragma unroll
      for (int s = 0; s < SEG; ++s)
        ring[k & 1][s] = fp[(size_t)j0[k + 2] + s * 4 + quad];
    }
  }
}

template<int CI, bool WF16>
__global__ __launch_bounds__(512, 6) void conv_mfma_v5(
    const _Float16* __restrict__ feats, const int* __restrict__ nbr,
    const _Float16* __restrict__ wT, float* __restrict__ outF,
    _Float16* __restrict__ outH, float* __restrict__ stOut) {
  // CI=64: 7 phases of <=4 k -> 4*64*72 halfs = 36.9 KB
  // CI=32: 4 phases of <=7 k -> 7*64*40 halfs = 35.8 KB
  constexpr int LDSH = (CI == 64) ? 4 * 64 * 72 : 7 * 64 * 40;
  __shared__ __align__(16) _Float16 ldsB[LDSH];
  __shared__ float bs[128];  // block-level stats reduce (sum | sumsq)

  int tid = threadIdx.x;
  int wave = tid >> 6, lane = tid & 63;
  int m = lane & 15, quad = lane >> 4;
  int vbase = (blockIdx.x * 8 + wave) * 16;  // 16 voxels per wave
  int v0 = vbase + m;
  v0 = v0 < NV ? v0 : NV - 1;
  const half8* fp = (const half8*)feats;

  if (tid < 128) bs[tid] = 0.f;  // ordered by stageB's first __syncthreads

  floatx4 acc[4];
#pragma unroll
  for (int nf = 0; nf < 4; ++nf) acc[nf] = (floatx4){0.f, 0.f, 0.f, 0.f};

  if constexpr (CI == 64) {
    stageB_v5<CI>(wT, ldsB, 0, 4, tid);  run_phase_v5<CI, 4>(fp, nbr, ldsB, 0,  v0, m, quad, acc);
    stageB_v5<CI>(wT, ldsB, 4, 4, tid);  run_phase_v5<CI, 4>(fp, nbr, ldsB, 4,  v0, m, quad, acc);
    stageB_v5<CI>(wT, ldsB, 8, 4, tid);  run_phase_v5<CI, 4>(fp, nbr, ldsB, 8,  v0, m, quad, acc);
    stageB_v5<CI>(wT, ldsB, 12, 4, tid); run_phase_v5<CI, 4>(fp, nbr, ldsB, 12, v0, m, quad, acc);
    stageB_v5<CI>(wT, ldsB, 16, 4, tid); run_phase_v5<CI, 4>(fp, nbr, ldsB, 16, v0, m, quad, acc);
    stageB_v5<CI>(wT, ldsB, 20, 4, tid); run_phase_v5<CI, 4>(fp, nbr, ldsB, 20, v0, m, quad, acc);
    stageB_v5<CI>(wT, ldsB, 24, 3, tid); run_phase_v5<CI, 3>(fp, nbr, ldsB, 24, v0, m, quad, acc);
  } else {
    stageB_v5<CI>(wT, ldsB, 0, 7, tid);  run_phase_v5<CI, 7>(fp, nbr, ldsB, 0,  v0, m, quad, acc);
    stageB_v5<CI>(wT, ldsB, 7, 7, tid);  run_phase_v5<CI, 7>(fp, nbr, ldsB, 7,  v0, m, quad, acc);
    stageB_v5<CI>(wT, ldsB, 14, 7, tid); run_phase_v5<CI, 7>(fp, nbr, ldsB, 14, v0, m, quad, acc);
    stageB_v5<CI>(wT, ldsB, 21, 6, tid); run_phase_v5<CI, 6>(fp, nbr, ldsB, 21, v0, m, quad, acc);
  }

  // epilogue: store + fused BN stats (sum / sumsq per channel)
  float s4[4], q4[4];
#pragma unroll
  for (int nf = 0; nf < 4; ++nf) {
    float s = 0.f, q = 0.f;
#pragma unroll
    for (int r = 0; r < 4; ++r) {
      int row = vbase + quad * 4 + r;
      if (row < NV) {
        float v = acc[nf][r];
        size_t o = (size_t)row * COUT_ + nf * 16 + m;
        if constexpr (WF16) outH[o] = (_Float16)v;
        else outF[o] = v;
        s += v;
        q = fmaf(v, v, q);
      }
    }
    s4[nf] = s; q4[nf] = q;
  }
  // reduce over the 4 quads: lanes m, m+16, m+32, m+48 hold channel nf*16+m
#pragma unroll
  for (int nf = 0; nf < 4; ++nf) {
    s4[nf] += __shfl_xor(s4[nf], 16); s4[nf] += __shfl_xor(s4[nf], 32);
    q4[nf] += __shfl_xor(q4[nf], 16); q4[nf] += __shfl_xor(q4[nf], 32);
  }
  if (quad == 0) {
#pragma unroll
    for (int nf = 0; nf < 4; ++nf) {
      atomicAdd(&bs[nf * 16 + m], s4[nf]);
      atomicAdd(&bs[64 + nf * 16 + m], q4[nf]);
    }
  }
  __syncthreads();
  if (tid < 128) atomicAdd(&stOut[tid], bs[tid]);
}

// ---- ident stats / BN finalize / epilogue kernels ----

__global__ __launch_bounds__(256) void ident_stats_kernel(
    const float* __restrict__ x, const float* __restrict__ wid,
    float* __restrict__ sums) {
  int lane = threadIdx.x & 63;
  int wv = blockIdx.x * 4 + (threadIdx.x >> 6);
  int nw = gridDim.x * 4;
  float wcol[CIN_];
#pragma unroll
  for (int ci = 0; ci < CIN_; ++ci) wcol[ci] = wid[ci * COUT_ + lane];
  float s = 0.f, ss = 0.f;
  for (int v = wv; v < NV; v += nw) {
    const float* xr = x + (size_t)v * CIN_;
    float d = 0.f;
#pragma unroll
    for (int ci = 0; ci < CIN_; ++ci) d = fmaf(xr[ci], wcol[ci], d);
    s += d;
    ss = fmaf(d, d, ss);
  }
  __shared__ float ls[128];
  if (threadIdx.x < 128) ls[threadIdx.x] = 0.f;
  __syncthreads();
  atomicAdd(&ls[lane], s);
  atomicAdd(&ls[64 + lane], ss);
  __syncthreads();
  if (threadIdx.x < 128) atomicAdd(&sums[threadIdx.x], ls[threadIdx.x]);
}

__global__ void finalize_kernel(const float* __restrict__ sums,
                                const float* __restrict__ g,
                                const float* __restrict__ b,
                                float* __restrict__ out) {
  int c = threadIdx.x;
  float m = sums[c] * (1.0f / NV);
  float var = sums[64 + c] * (1.0f / NV) - m * m;
  float sc = g[c] / sqrtf(var + EPS_);
  out[c] = sc;
  out[64 + c] = b[c] - m * sc;
}

__global__ __launch_bounds__(256) void bnrelu_f16_kernel(
    _Float16* __restrict__ y, const float* __restrict__ scsh) {
  size_t q = (size_t)blockIdx.x * 256 + threadIdx.x;
  if (q >= (size_t)NV * COUT_ / 8) return;
  int c0 = (int)(q & 7) * 8;
  half8 v = ((const half8*)y)[q];
#pragma unroll
  for (int jj = 0; jj < 8; ++jj) {
    float f = fmaxf(fmaf((float)v[jj], scsh[c0 + jj], scsh[64 + c0 + jj]), 0.f);
    v[jj] = (_Float16)f;
  }
  ((half8*)y)[q] = v;
}

__global__ __launch_bounds__(256) void final_kernel(
    const float* __restrict__ x, const float* __restrict__ wid,
    float* __restrict__ y2out, const float* __restrict__ ss2,
    const float* __restrict__ ssid) {
  int lane = threadIdx.x & 63;
  int wv = blockIdx.x * 4 + (threadIdx.x >> 6);
  int nw = gridDim.x * 4;
  float wcol[CIN_];
#pragma unroll
  for (int ci = 0; ci < CIN_; ++ci) wcol[ci] = wid[ci * COUT_ + lane];
  float sc2 = ss2[lane], sh2 = ss2[64 + lane];
  float sci = ssid[lane], shi = ssid[64 + lane];
  for (int v = wv; v < NV; v += nw) {
    const float* xr = x + (size_t)v * CIN_;
    float d = 0.f;
#pragma unroll
    for (int ci = 0; ci < CIN_; ++ci) d = fmaf(xr[ci], wcol[ci], d);
    size_t o = (size_t)v * COUT_ + lane;
    float r = fmaf(y2out[o], sc2, sh2) + fmaf(d, sci, shi);
    y2out[o] = fmaxf(r, 0.f);
  }
}

extern "C" void kernel_launch(void* const* d_in, const int* in_sizes, int n_in,
                              void* d_out, int out_size, void* d_ws, size_t ws_size,
                              hipStream_t stream) {
  const float* x   = (const float*)d_in[0];
  const int*   nbr = (const int*)d_in[1];
  const float* w1  = (const float*)d_in[2];
  const float* g1  = (const float*)d_in[3];
  const float* b1  = (const float*)d_in[4];
  const float* w2  = (const float*)d_in[5];
  const float* g2  = (const float*)d_in[6];
  const float* b2  = (const float*)d_in[7];
  const float* wid = (const float*)d_in[8];
  const float* gid = (const float*)d_in[9];
  const float* bid = (const float*)d_in[10];
  float* out = (float*)d_out;

  _Float16* y1h = (_Float16*)d_ws;
  _Float16* xh  = y1h + (size_t)NV * COUT_;
  _Float16* wT1 = xh + (size_t)NV * CIN_;
  _Float16* wT2 = wT1 + KOFF * COUT_ * CIN_;
  float*    st  = (float*)(wT2 + KOFF * COUT_ * COUT_);

  const int NWG = (NV + 127) / 128;  // 512 thr = 8 waves x 16 voxels

  zero_stats_kernel<<<1, 384, 0, stream>>>(st);
  cast_x_kernel<<<(NV * CIN_ / 8 + 255) / 256, 256, 0, stream>>>(x, xh);
  wtrans_kernel<<<(KOFF * CIN_ * COUT_ + 255) / 256, 256, 0, stream>>>(w1, wT1, CIN_);
  wtrans_kernel<<<(KOFF * COUT_ * COUT_ + 255) / 256, 256, 0, stream>>>(w2, wT2, COUT_);

  // conv1 with fused BN1 stats -> st[0:128)
  conv_mfma_v5<CIN_, true><<<NWG, 512, 0, stream>>>(xh, nbr, wT1, nullptr, y1h, st + 0);
  ident_stats_kernel<<<2048, 256, 0, stream>>>(x, wid, st + 256);
  finalize_kernel<<<1, 64, 0, stream>>>(st + 0, g1, b1, st + 384);
  finalize_kernel<<<1, 64, 0, stream>>>(st + 256, gid, bid, st + 640);
  bnrelu_f16_kernel<<<(NV * COUT_ / 8 + 255) / 256, 256, 0, stream>>>(y1h, st + 384);

  // conv2 with fused BN2 stats -> st[128:256)
  conv_mfma_v5<COUT_, false><<<NWG, 512, 0, stream>>>(y1h, nbr, wT2, out, nullptr, st + 128);
  finalize_kernel<<<1, 64, 0, stream>>>(st + 128, g2, b2, st + 512);
  final_kernel<<<4096, 256, 0, stream>>>(x, wid, out, st + 512, st + 640);
}

// Round 3
// 1194.996 us; speedup vs baseline: 4.2437x; 3.9602x over previous
//
#include <hip/hip_runtime.h>

#define NV 500000
#define KOFF 27
#define CIN_ 32
#define COUT_ 64
#define EPS_ 1e-5f

typedef __attribute__((ext_vector_type(8))) _Float16 half8;
typedef __attribute__((ext_vector_type(4))) float floatx4;

// ws layout: y1h NV*64 f16 | xh NV*32 f16 | wT1 27*64*32 f16 | wT2 27*64*64 f16 | st 768 f32

__global__ void zero_stats_kernel(float* __restrict__ s) {
  if (threadIdx.x < 384) s[threadIdx.x] = 0.f;
}

__global__ __launch_bounds__(256) void cast_x_kernel(
    const float* __restrict__ x, _Float16* __restrict__ xh) {
  size_t q = (size_t)blockIdx.x * 256 + threadIdx.x;
  if (q >= (size_t)NV * CIN_ / 8) return;
  const float4* xp = (const float4*)x;
  float4 a = xp[2 * q], b = xp[2 * q + 1];
  half8 h;
  h[0] = (_Float16)a.x; h[1] = (_Float16)a.y; h[2] = (_Float16)a.z; h[3] = (_Float16)a.w;
  h[4] = (_Float16)b.x; h[5] = (_Float16)b.y; h[6] = (_Float16)b.z; h[7] = (_Float16)b.w;
  ((half8*)xh)[q] = h;
}

// wT[k][co][ci] = (f16) w[k][ci][co]
__global__ void wtrans_kernel(const float* __restrict__ w,
                              _Float16* __restrict__ wT, int CI) {
  int t = blockIdx.x * 256 + threadIdx.x;
  int total = KOFF * CI * COUT_;
  if (t >= total) return;
  int k = t / (CI * COUT_);
  int r = t % (CI * COUT_);
  int co = r / CI;
  int ci = r % CI;
  wT[t] = (_Float16)w[(k * CI + ci) * COUT_ + co];
}

// ---- conv v6: 256-thr blocks (4 waves), 16 voxels/wave, KPC=3 phases ----
// Rounds 1-2 lesson: hipcc reads __launch_bounds__ arg2 as min BLOCKS/CU
// (CUDA semantics): (512,6) -> 12 waves/EU -> 42-reg cap -> 5.5GB scratch.
// 256-thr blocks make both interpretations coincide: (256,5) -> cap 102
// under either reading. LDS/block 28KB (CI=64) / 16KB (CI=32) -> 5-8
// resident blocks/CU = 20-32 waves, block-local barriers never drain the CU.

template<int CI>
__device__ __forceinline__ void stageB_v6(const _Float16* __restrict__ wT,
                                          _Float16* __restrict__ lds,
                                          int k0, int kp, int tid) {
  __syncthreads();  // all waves done reading previous phase's LDS
  const int segs = CI / 8;
  const int chunks = kp * COUT_ * segs;
  for (int idx = tid; idx < chunks; idx += 256) {
    int row = idx / segs;
    int s = idx - row * segs;
    half8 v = *(const half8*)(wT + ((size_t)k0 * COUT_ + row) * CI + s * 8);
    *(half8*)(lds + (size_t)row * (CI + 8) + s * 8) = v;
  }
  __syncthreads();
}

template<int CI, int KPC, int D>
__device__ __forceinline__ void run_phase_v6(
    const half8* __restrict__ fp, const int* __restrict__ nbr,
    const _Float16* __restrict__ lds, int k0,
    int v0, int m, int quad, floatx4 acc[4]) {
  constexpr int SEG = CI / 32;
  constexpr int ROWH8 = CI / 8;

  // preload all phase indices first (vmcnt drains in order)
  int j0[KPC];
#pragma unroll
  for (int k = 0; k < KPC; ++k) j0[k] = nbr[(k0 + k) * NV + v0] * ROWH8;

  half8 ring[D][SEG];
#pragma unroll
  for (int p = 0; p < D; ++p)
#pragma unroll
    for (int s = 0; s < SEG; ++s)
      ring[p][s] = fp[(size_t)j0[p] + s * 4 + quad];

#pragma unroll
  for (int k = 0; k < KPC; ++k) {
    const _Float16* bk = lds + (size_t)k * COUT_ * (CI + 8);
#pragma unroll
    for (int s = 0; s < SEG; ++s)
#pragma unroll
      for (int nf = 0; nf < 4; ++nf) {
        half8 bf = *(const half8*)(bk + (nf * 16 + m) * (CI + 8) + s * 32 + quad * 8);
        acc[nf] = __builtin_amdgcn_mfma_f32_16x16x32_f16(ring[k % D][s], bf, acc[nf], 0, 0, 0);
      }
    if (k + D < KPC) {
#pragma unroll
      for (int s = 0; s < SEG; ++s)
        ring[k % D][s] = fp[(size_t)j0[k + D] + s * 4 + quad];
    }
  }
}

template<int CI, bool WF16>
__global__ __launch_bounds__(256, 5) void conv_mfma_v6(
    const _Float16* __restrict__ feats, const int* __restrict__ nbr,
    const _Float16* __restrict__ wT, float* __restrict__ outF,
    _Float16* __restrict__ outH, float* __restrict__ stOut) {
  // 3 k-offsets per phase: CI=64 -> 3*64*72*2B = 27.6KB; CI=32 -> 15.4KB
  constexpr int LDSH = 3 * 64 * (CI + 8);
  __shared__ __align__(16) _Float16 ldsB[LDSH];
  __shared__ float bs[128];  // block-level stats reduce (sum | sumsq)

  int tid = threadIdx.x;
  int wave = tid >> 6, lane = tid & 63;
  int m = lane & 15, quad = lane >> 4;
  int vbase = (blockIdx.x * 4 + wave) * 16;  // 16 voxels per wave
  int v0 = vbase + m;
  v0 = v0 < NV ? v0 : NV - 1;
  const half8* fp = (const half8*)feats;

  if (tid < 128) bs[tid] = 0.f;  // ordered by stageB's first __syncthreads

  floatx4 acc[4];
#pragma unroll
  for (int nf = 0; nf < 4; ++nf) acc[nf] = (floatx4){0.f, 0.f, 0.f, 0.f};

#pragma unroll
  for (int ph = 0; ph < 9; ++ph) {
    stageB_v6<CI>(wT, ldsB, ph * 3, 3, tid);
    run_phase_v6<CI, 3, 3>(fp, nbr, ldsB, ph * 3, v0, m, quad, acc);
  }

  // epilogue: store + fused BN stats (sum / sumsq per channel)
  float s4[4], q4[4];
#pragma unroll
  for (int nf = 0; nf < 4; ++nf) {
    float s = 0.f, q = 0.f;
#pragma unroll
    for (int r = 0; r < 4; ++r) {
      int row = vbase + quad * 4 + r;
      if (row < NV) {
        float v = acc[nf][r];
        size_t o = (size_t)row * COUT_ + nf * 16 + m;
        if constexpr (WF16) outH[o] = (_Float16)v;
        else outF[o] = v;
        s += v;
        q = fmaf(v, v, q);
      }
    }
    s4[nf] = s; q4[nf] = q;
  }
  // reduce over the 4 quads: lanes m, m+16, m+32, m+48 hold channel nf*16+m
#pragma unroll
  for (int nf = 0; nf < 4; ++nf) {
    s4[nf] += __shfl_xor(s4[nf], 16); s4[nf] += __shfl_xor(s4[nf], 32);
    q4[nf] += __shfl_xor(q4[nf], 16); q4[nf] += __shfl_xor(q4[nf], 32);
  }
  if (quad == 0) {
#pragma unroll
    for (int nf = 0; nf < 4; ++nf) {
      atomicAdd(&bs[nf * 16 + m], s4[nf]);
      atomicAdd(&bs[64 + nf * 16 + m], q4[nf]);
    }
  }
  __syncthreads();
  if (tid < 128) atomicAdd(&stOut[tid], bs[tid]);
}

// ---- ident stats / BN finalize / epilogue kernels ----

__global__ __launch_bounds__(256) void ident_stats_kernel(
    const float* __restrict__ x, const float* __restrict__ wid,
    float* __restrict__ sums) {
  int lane = threadIdx.x & 63;
  int wv = blockIdx.x * 4 + (threadIdx.x >> 6);
  int nw = gridDim.x * 4;
  float wcol[CIN_];
#pragma unroll
  for (int ci = 0; ci < CIN_; ++ci) wcol[ci] = wid[ci * COUT_ + lane];
  float s = 0.f, ss = 0.f;
  for (int v = wv; v < NV; v += nw) {
    const float* xr = x + (size_t)v * CIN_;
    float d = 0.f;
#pragma unroll
    for (int ci = 0; ci < CIN_; ++ci) d = fmaf(xr[ci], wcol[ci], d);
    s += d;
    ss = fmaf(d, d, ss);
  }
  __shared__ float ls[128];
  if (threadIdx.x < 128) ls[threadIdx.x] = 0.f;
  __syncthreads();
  atomicAdd(&ls[lane], s);
  atomicAdd(&ls[64 + lane], ss);
  __syncthreads();
  if (threadIdx.x < 128) atomicAdd(&sums[threadIdx.x], ls[threadIdx.x]);
}

__global__ void finalize_kernel(const float* __restrict__ sums,
                                const float* __restrict__ g,
                                const float* __restrict__ b,
                                float* __restrict__ out) {
  int c = threadIdx.x;
  float m = sums[c] * (1.0f / NV);
  float var = sums[64 + c] * (1.0f / NV) - m * m;
  float sc = g[c] / sqrtf(var + EPS_);
  out[c] = sc;
  out[64 + c] = b[c] - m * sc;
}

__global__ __launch_bounds__(256) void bnrelu_f16_kernel(
    _Float16* __restrict__ y, const float* __restrict__ scsh) {
  size_t q = (size_t)blockIdx.x * 256 + threadIdx.x;
  if (q >= (size_t)NV * COUT_ / 8) return;
  int c0 = (int)(q & 7) * 8;
  half8 v = ((const half8*)y)[q];
#pragma unroll
  for (int jj = 0; jj < 8; ++jj) {
    float f = fmaxf(fmaf((float)v[jj], scsh[c0 + jj], scsh[64 + c0 + jj]), 0.f);
    v[jj] = (_Float16)f;
  }
  ((half8*)y)[q] = v;
}

__global__ __launch_bounds__(256) void final_kernel(
    const float* __restrict__ x, const float* __restrict__ wid,
    float* __restrict__ y2out, const float* __restrict__ ss2,
    const float* __restrict__ ssid) {
  int lane = threadIdx.x & 63;
  int wv = blockIdx.x * 4 + (threadIdx.x >> 6);
  int nw = gridDim.x * 4;
  float wcol[CIN_];
#pragma unroll
  for (int ci = 0; ci < CIN_; ++ci) wcol[ci] = wid[ci * COUT_ + lane];
  float sc2 = ss2[lane], sh2 = ss2[64 + lane];
  float sci = ssid[lane], shi = ssid[64 + lane];
  for (int v = wv; v < NV; v += nw) {
    const float* xr = x + (size_t)v * CIN_;
    float d = 0.f;
#pragma unroll
    for (int ci = 0; ci < CIN_; ++ci) d = fmaf(xr[ci], wcol[ci], d);
    size_t o = (size_t)v * COUT_ + lane;
    float r = fmaf(y2out[o], sc2, sh2) + fmaf(d, sci, shi);
    y2out[o] = fmaxf(r, 0.f);
  }
}

extern "C" void kernel_launch(void* const* d_in, const int* in_sizes, int n_in,
                              void* d_out, int out_size, void* d_ws, size_t ws_size,
                              hipStream_t stream) {
  const float* x   = (const float*)d_in[0];
  const int*   nbr = (const int*)d_in[1];
  const float* w1  = (const float*)d_in[2];
  const float* g1  = (const float*)d_in[3];
  const float* b1  = (const float*)d_in[4];
  const float* w2  = (const float*)d_in[5];
  const float* g2  = (const float*)d_in[6];
  const float* b2  = (const float*)d_in[7];
  const float* wid = (const float*)d_in[8];
  const float* gid = (const float*)d_in[9];
  const float* bid = (const float*)d_in[10];
  float* out = (float*)d_out;

  _Float16* y1h = (_Float16*)d_ws;
  _Float16* xh  = y1h + (size_t)NV * COUT_;
  _Float16* wT1 = xh + (size_t)NV * CIN_;
  _Float16* wT2 = wT1 + KOFF * COUT_ * CIN_;
  float*    st  = (float*)(wT2 + KOFF * COUT_ * COUT_);

  const int NWG = (NV + 63) / 64;  // 256 thr = 4 waves x 16 voxels

  zero_stats_kernel<<<1, 384, 0, stream>>>(st);
  cast_x_kernel<<<(NV * CIN_ / 8 + 255) / 256, 256, 0, stream>>>(x, xh);
  wtrans_kernel<<<(KOFF * CIN_ * COUT_ + 255) / 256, 256, 0, stream>>>(w1, wT1, CIN_);
  wtrans_kernel<<<(KOFF * COUT_ * COUT_ + 255) / 256, 256, 0, stream>>>(w2, wT2, COUT_);

  // conv1 with fused BN1 stats -> st[0:128)
  conv_mfma_v6<CIN_, true><<<NWG, 256, 0, stream>>>(xh, nbr, wT1, nullptr, y1h, st + 0);
  ident_stats_kernel<<<2048, 256, 0, stream>>>(x, wid, st + 256);
  finalize_kernel<<<1, 64, 0, stream>>>(st + 0, g1, b1, st + 384);
  finalize_kernel<<<1, 64, 0, stream>>>(st + 256, gid, bid, st + 640);
  bnrelu_f16_kernel<<<(NV * COUT_ / 8 + 255) / 256, 256, 0, stream>>>(y1h, st + 384);

  // conv2 with fused BN2 stats -> st[128:256)
  conv_mfma_v6<COUT_, false><<<NWG, 256, 0, stream>>>(y1h, nbr, wT2, out, nullptr, st + 128);
  finalize_kernel<<<1, 64, 0, stream>>>(st + 128, g2, b2, st + 512);
  final_kernel<<<4096, 256, 0, stream>>>(x, wid, out, st + 512, st + 640);
}